// Round 1
// baseline (15505.255 us; speedup 1.0000x reference)
//
#include <hip/hip_runtime.h>

typedef __attribute__((ext_vector_type(8))) short short8;
typedef __attribute__((ext_vector_type(4))) float f32x4;

#define MFMA_B16(a, b, c) __builtin_amdgcn_mfma_f32_16x16x32_bf16((a), (b), (c), 0, 0, 0)

#define TSTEPS 256
#define NBATCH 64
#define HID    512

__device__ __forceinline__ unsigned short f2bf(float f) {
  unsigned int u = __float_as_uint(f);
  u += 0x7fffu + ((u >> 16) & 1u);
  return (unsigned short)(u >> 16);
}
__device__ __forceinline__ float bf2f(unsigned short s) {
  return __uint_as_float(((unsigned int)s) << 16);
}
__device__ __forceinline__ float sigm(float x) { return 1.0f / (1.0f + __expf(-x)); }
__device__ __forceinline__ float tanhf_(float x) {
  float xc = fminf(fmaxf(x, -15.0f), 15.0f);
  float e = __expf(2.0f * xc);
  return (e - 1.0f) / (e + 1.0f);
}

// 16B load that bypasses L1/L2 (coherent at device scope, reads LLC)
__device__ __forceinline__ short8 ld_llc16(const unsigned short* p) {
  union { unsigned long long q[2]; short8 s; } u;
  unsigned long long* a = (unsigned long long*)p;
  u.q[0] = __hip_atomic_load(a,     __ATOMIC_RELAXED, __HIP_MEMORY_SCOPE_AGENT);
  u.q[1] = __hip_atomic_load(a + 1, __ATOMIC_RELAXED, __HIP_MEMORY_SCOPE_AGENT);
  return u.s;
}

__global__ void cvt_kernel(const float* __restrict__ src, unsigned short* __restrict__ dst, int n4) {
  int i = blockIdx.x * blockDim.x + threadIdx.x;
  int stride = gridDim.x * blockDim.x;
  for (; i < n4; i += stride) {
    f32x4 v = ((const f32x4*)src)[i];
    union { unsigned short u[4]; unsigned long long q; } o;
    o.u[0] = f2bf(v[0]); o.u[1] = f2bf(v[1]); o.u[2] = f2bf(v[2]); o.u[3] = f2bf(v[3]);
    ((unsigned long long*)dst)[i] = o.q;
  }
}

// Persistent bidirectional LSTM layer scan.
// Grid: 128 blocks x 256 threads. Blocks 0..63 forward, 64..127 backward.
// Each block owns 8 hidden units (32 gate rows: i,f,g,o x 8).
// h exchanged via ws ping-pong (bf16) through LLC; c stays in registers.
template<int DIN>
__global__ __launch_bounds__(256, 1)
void scan_kernel(const unsigned short* __restrict__ act_in,
                 unsigned short* __restrict__ act_out,
                 const unsigned short* __restrict__ wih_f,
                 const unsigned short* __restrict__ whh_f,
                 const float* __restrict__ bias_f,
                 const unsigned short* __restrict__ wih_b,
                 const unsigned short* __restrict__ whh_b,
                 const float* __restrict__ bias_b,
                 const float* __restrict__ init_f,
                 const float* __restrict__ init_b,
                 const float* __restrict__ masks,
                 unsigned short* hb,          // [2 dirs][2 slots][64*512] bf16
                 unsigned int* bar,           // [dir][2] = {cnt, gen}
                 float* out_h, float* out_c)  // per-layer slices of d_out
{
  const int bid  = blockIdx.x;
  const int dir  = bid >> 6;
  const int j0   = (bid & 63) << 3;
  const int lane = threadIdx.x & 63;
  const int wave = threadIdx.x >> 6;
  const int n    = lane & 15;
  const int kb   = lane >> 4;

  const unsigned short* wih = dir ? wih_b : wih_f;
  const unsigned short* whh = dir ? whh_b : whh_f;
  const float* bias = dir ? bias_b : bias_f;
  const float* init = dir ? init_b : init_f;
  unsigned int* cnt = bar + dir * 2;
  unsigned int* gen = bar + dir * 2 + 1;
  unsigned short* hbd = hb + dir * (2 * NBATCH * HID);
  float* oh = out_h + dir * (NBATCH * HID);
  float* oc = out_c + dir * (NBATCH * HID);

  // gate-row indices for the two 16-wide n-tiles: tile0 = [i(8)|f(8)], tile1 = [g(8)|o(8)]
  const int wr0 = (n < 8) ? (j0 + n) : (512 + j0 + (n - 8));
  const int wr1 = (n < 8) ? (1024 + j0 + n) : (1536 + j0 + (n - 8));
  const float bb0 = bias[wr0];
  const float bb1 = bias[wr1];

  const unsigned short* wih0 = wih + wr0 * DIN + kb * 8;
  const unsigned short* wih1 = wih + wr1 * DIN + kb * 8;
  const unsigned short* whh0 = whh + wr0 * HID + kb * 8;
  const unsigned short* whh1 = whh + wr1 * HID + kb * 8;

  // h0 init into slot 0 (this block's 64x8 slice)
  for (int e = threadIdx.x; e < 512; e += 256) {
    int b = e >> 3, u = e & 7;
    hbd[b * HID + j0 + u] = f2bf(init[j0 + u]);
  }
  float cs0, cs1, cs2, cs3;
  cs0 = cs1 = cs2 = cs3 = init[512 + j0 + (n & 7)];

  __syncthreads();
  if (threadIdx.x == 0) {
    unsigned int old = __hip_atomic_fetch_add(cnt, 1u, __ATOMIC_RELEASE, __HIP_MEMORY_SCOPE_AGENT);
    if (((old + 1) & 63u) == 0u)
      __hip_atomic_store(gen, (old + 1) >> 6, __ATOMIC_RELEASE, __HIP_MEMORY_SCOPE_AGENT);
  }

  f32x4 acc0e = (f32x4){bb0, bb0, bb0, bb0};
  f32x4 acc0o = (f32x4){0.f, 0.f, 0.f, 0.f};
  f32x4 acc1e = (f32x4){bb1, bb1, bb1, bb1};
  f32x4 acc1o = (f32x4){0.f, 0.f, 0.f, 0.f};

  // input-projection part for t = 0 (no h dependency)
  {
    const int tt0 = dir ? (TSTEPS - 1) : 0;
    const unsigned short* arow = act_in + (tt0 * NBATCH + wave * 16 + n) * DIN + kb * 8;
    #pragma unroll
    for (int kt = 0; kt < DIN / 32; kt += 2) {
      short8 a0 = *(const short8*)(arow + kt * 32);
      short8 a1 = *(const short8*)(arow + kt * 32 + 32);
      acc0e = MFMA_B16(a0, *(const short8*)(wih0 + kt * 32), acc0e);
      acc1e = MFMA_B16(a0, *(const short8*)(wih1 + kt * 32), acc1e);
      acc0o = MFMA_B16(a1, *(const short8*)(wih0 + kt * 32 + 32), acc0o);
      acc1o = MFMA_B16(a1, *(const short8*)(wih1 + kt * 32 + 32), acc1o);
    }
  }

  for (int t = 0; t < TSTEPS; ++t) {
    // wait for h(t-1)
    if (threadIdx.x == 0) {
      while (__hip_atomic_load(gen, __ATOMIC_RELAXED, __HIP_MEMORY_SCOPE_AGENT) < (unsigned int)(t + 1))
        __builtin_amdgcn_s_sleep(1);
    }
    __syncthreads();

    // recurrent part: h(t-1) @ Whh_slice
    {
      const unsigned short* hrow = hbd + (t & 1) * (NBATCH * HID) + (wave * 16 + n) * HID + kb * 8;
      #pragma unroll
      for (int kt = 0; kt < 16; kt += 2) {
        short8 a0 = ld_llc16(hrow + kt * 32);
        short8 a1 = ld_llc16(hrow + kt * 32 + 32);
        acc0e = MFMA_B16(a0, *(const short8*)(whh0 + kt * 32), acc0e);
        acc1e = MFMA_B16(a0, *(const short8*)(whh1 + kt * 32), acc1e);
        acc0o = MFMA_B16(a1, *(const short8*)(whh0 + kt * 32 + 32), acc0o);
        acc1o = MFMA_B16(a1, *(const short8*)(whh1 + kt * 32 + 32), acc1o);
      }
    }

    f32x4 acc0 = acc0e + acc0o;
    f32x4 acc1 = acc1e + acc1o;
    // pair (i,f) and (g,o) across lane^8
    f32x4 oth0, oth1;
    #pragma unroll
    for (int r = 0; r < 4; ++r) {
      oth0[r] = __shfl_xor(acc0[r], 8, 64);
      oth1[r] = __shfl_xor(acc1[r], 8, 64);
    }
    const bool hi = (n >= 8);
    const int tt = dir ? (TSTEPS - 1 - t) : t;
    f32x4 mk = *(const f32x4*)(masks + tt * NBATCH + wave * 16 + kb * 4);

    float hv[4], cz[4] = {cs0, cs1, cs2, cs3};
    #pragma unroll
    for (int i = 0; i < 4; ++i) {
      float vi = hi ? oth0[i] : acc0[i];
      float vf = hi ? acc0[i] : oth0[i];
      float vg = hi ? oth1[i] : acc1[i];
      float vo = hi ? acc1[i] : oth1[i];
      float cn = (sigm(vf) * cz[i] + sigm(vi) * tanhf_(vg)) * mk[i];
      hv[i] = sigm(vo) * tanhf_(cn) * mk[i];
      cz[i] = cn;
    }
    cs0 = cz[0]; cs1 = cz[1]; cs2 = cz[2]; cs3 = cz[3];

    if (!hi) {
      unsigned short* hout = hbd + ((t + 1) & 1) * (NBATCH * HID);
      const int jj = j0 + n;
      #pragma unroll
      for (int i = 0; i < 4; ++i) {
        const int b = wave * 16 + kb * 4 + i;
        unsigned short h16 = f2bf(hv[i]);
        hout[b * HID + jj] = h16;
        act_out[(tt * NBATCH + b) * (2 * HID) + dir * HID + jj] = h16;
        if (t == TSTEPS - 1) {
          oh[b * HID + jj] = hv[i];
          oc[b * HID + jj] = cz[i];
        }
      }
    }
    __syncthreads();
    // arrive: RELEASE flushes our L2 (incl. all waves' h stores) to LLC
    if (threadIdx.x == 0) {
      unsigned int old = __hip_atomic_fetch_add(cnt, 1u, __ATOMIC_RELEASE, __HIP_MEMORY_SCOPE_AGENT);
      if (((old + 1) & 63u) == 0u)
        __hip_atomic_store(gen, (old + 1) >> 6, __ATOMIC_RELEASE, __HIP_MEMORY_SCOPE_AGENT);
    }
    // overlap: input-projection part for t+1 while other blocks finish
    if (t + 1 < TSTEPS) {
      acc0e = (f32x4){bb0, bb0, bb0, bb0};
      acc0o = (f32x4){0.f, 0.f, 0.f, 0.f};
      acc1e = (f32x4){bb1, bb1, bb1, bb1};
      acc1o = (f32x4){0.f, 0.f, 0.f, 0.f};
      const int tt2 = dir ? (TSTEPS - 2 - t) : (t + 1);
      const unsigned short* arow = act_in + (tt2 * NBATCH + wave * 16 + n) * DIN + kb * 8;
      #pragma unroll
      for (int kt = 0; kt < DIN / 32; kt += 2) {
        short8 a0 = *(const short8*)(arow + kt * 32);
        short8 a1 = *(const short8*)(arow + kt * 32 + 32);
        acc0e = MFMA_B16(a0, *(const short8*)(wih0 + kt * 32), acc0e);
        acc1e = MFMA_B16(a0, *(const short8*)(wih1 + kt * 32), acc1e);
        acc0o = MFMA_B16(a1, *(const short8*)(wih0 + kt * 32 + 32), acc0o);
        acc1o = MFMA_B16(a1, *(const short8*)(wih1 + kt * 32 + 32), acc1o);
      }
    }
  }
}

// Highway gate: g = sigmoid(raw @ projW^T + projb); out = g*raw + (1-g)*inp
// FINAL=0: write bf16 in-place over inp. FINAL=1: write fp32 to outf.
template<int FINAL>
__global__ __launch_bounds__(256)
void highway_kernel(const unsigned short* __restrict__ raw,
                    unsigned short* __restrict__ inp,
                    const unsigned short* __restrict__ pw,
                    const float* __restrict__ pb,
                    float* __restrict__ outf)
{
  const int lane = threadIdx.x & 63;
  const int wave = threadIdx.x >> 6;
  const int n = lane & 15, kb = lane >> 4;
  const int r0 = blockIdx.x * 64 + wave * 16;
  const int c0 = blockIdx.y * 64;

  f32x4 acc[4];
  #pragma unroll
  for (int nt = 0; nt < 4; ++nt) {
    float b = pb[c0 + nt * 16 + n];
    acc[nt] = (f32x4){b, b, b, b};
  }
  const unsigned short* arow = raw + (r0 + n) * 1024 + kb * 8;
  #pragma unroll 4
  for (int kt = 0; kt < 32; ++kt) {
    short8 a = *(const short8*)(arow + kt * 32);
    #pragma unroll
    for (int nt = 0; nt < 4; ++nt) {
      short8 b = *(const short8*)(pw + (c0 + nt * 16 + n) * 1024 + kt * 32 + kb * 8);
      acc[nt] = MFMA_B16(a, b, acc[nt]);
    }
  }
  #pragma unroll
  for (int nt = 0; nt < 4; ++nt) {
    #pragma unroll
    for (int i = 0; i < 4; ++i) {
      int row = r0 + kb * 4 + i;
      int col = c0 + nt * 16 + n;
      float g = sigm(acc[nt][i]);
      float rv = bf2f(raw[row * 1024 + col]);
      float iv = bf2f(inp[row * 1024 + col]);
      float ov = g * rv + (1.0f - g) * iv;
      if (FINAL) outf[row * 1024 + col] = ov;
      else       inp[row * 1024 + col] = f2bf(ov);
    }
  }
}

extern "C" void kernel_launch(void* const* d_in, const int* in_sizes, int n_in,
                              void* d_out, int out_size, void* d_ws, size_t ws_size,
                              hipStream_t stream) {
  const float* x     = (const float*)d_in[0];
  const float* masks = (const float*)d_in[1];
  const float* fWih0 = (const float*)d_in[2];
  const float* fWihR = (const float*)d_in[3];
  const float* fWhh  = (const float*)d_in[4];
  const float* fb    = (const float*)d_in[5];
  const float* bWih0 = (const float*)d_in[6];
  const float* bWihR = (const float*)d_in[7];
  const float* bWhh  = (const float*)d_in[8];
  const float* bbias = (const float*)d_in[9];
  const float* fInit = (const float*)d_in[10];
  const float* bInit = (const float*)d_in[11];
  const float* projW = (const float*)d_in[12];
  const float* projB = (const float*)d_in[13];
  float* out = (float*)d_out;

  char* ws = (char*)d_ws;
  unsigned short* bufA = (unsigned short*)(ws + 0);           // 33,554,432 B
  unsigned short* bufB = (unsigned short*)(ws + 33554432);    // 33,554,432 B
  unsigned short* xbf  = (unsigned short*)(ws + 67108864);    // 16,777,216 B
  unsigned short* wf0  = (unsigned short*)(ws + 83886080);    //  2,097,152 B
  unsigned short* wf12 = (unsigned short*)(ws + 85983232);    //  8,388,608 B
  unsigned short* whf  = (unsigned short*)(ws + 94371840);    //  6,291,456 B
  unsigned short* wb0  = (unsigned short*)(ws + 100663296);   //  2,097,152 B
  unsigned short* wb12 = (unsigned short*)(ws + 102760448);   //  8,388,608 B
  unsigned short* whb  = (unsigned short*)(ws + 111149056);   //  6,291,456 B
  unsigned short* pj   = (unsigned short*)(ws + 117440512);   //  4,194,304 B
  unsigned short* hbuf = (unsigned short*)(ws + 121634816);   //    262,144 B
  unsigned int*   bar  = (unsigned int*)(ws + 121896960);     //        256 B

  hipMemsetAsync(bar, 0, 256, stream);

  cvt_kernel<<<1024, 256, 0, stream>>>(x,     xbf,  (256*64*512)   / 4);
  cvt_kernel<<<1024, 256, 0, stream>>>(fWih0, wf0,  (2048*512)     / 4);
  cvt_kernel<<<1024, 256, 0, stream>>>(fWihR, wf12, (2*2048*1024)  / 4);
  cvt_kernel<<<1024, 256, 0, stream>>>(fWhh,  whf,  (3*2048*512)   / 4);
  cvt_kernel<<<1024, 256, 0, stream>>>(bWih0, wb0,  (2048*512)     / 4);
  cvt_kernel<<<1024, 256, 0, stream>>>(bWihR, wb12, (2*2048*1024)  / 4);
  cvt_kernel<<<1024, 256, 0, stream>>>(bWhh,  whb,  (3*2048*512)   / 4);
  cvt_kernel<<<1024, 256, 0, stream>>>(projW, pj,   (2*1024*1024)  / 4);

  float* outH = out + 16777216;
  float* outC = out + 16777216 + 6*64*512;

  // layer 0
  scan_kernel<512><<<128, 256, 0, stream>>>(
      xbf, bufA,
      wf0, whf, fb,
      wb0, whb, bbias,
      fInit, bInit,
      masks, hbuf, bar,
      outH, outC);
  // layer 1
  scan_kernel<1024><<<128, 256, 0, stream>>>(
      bufA, bufB,
      wf12,               whf + 2048*512,   fb + 2048,
      wb12,               whb + 2048*512,   bbias + 2048,
      fInit + 1024, bInit + 1024,
      masks, hbuf, bar + 4,
      outH + 2*64*512, outC + 2*64*512);
  highway_kernel<0><<<dim3(256, 16), 256, 0, stream>>>(bufB, bufA, pj, projB, nullptr);
  // layer 2
  scan_kernel<1024><<<128, 256, 0, stream>>>(
      bufA, bufB,
      wf12 + 2048*1024,   whf + 2*2048*512, fb + 2*2048,
      wb12 + 2048*1024,   whb + 2*2048*512, bbias + 2*2048,
      fInit + 2048, bInit + 2048,
      masks, hbuf, bar + 8,
      outH + 4*64*512, outC + 4*64*512);
  highway_kernel<1><<<dim3(256, 16), 256, 0, stream>>>(bufB, bufA, pj + 1024*1024, projB + 1024, out);
}